// Round 11
// baseline (107.388 us; speedup 1.0000x reference)
//
#include <hip/hip_runtime.h>
#include <hip/hip_bf16.h>
#include <math.h>

#define P 4096          // number of (even,odd) pairs = B/2
#define DIM 128
#define EPS_F 1e-8f
#define LOG2E 1.4426950408889634f
#define LN2   0.6931471805599453f
#define MLG2  LOG2E     // MARGIN(=1)*log2e folded into acc init

#define RPB 128         // rows per block (4 waves x 32)
#define CPB 256         // cols per block (4 tiles of 64)
#define TILE_COLS 64
#define NTILES 4
#define NRB (P / RPB)   // 32 row-blocks
#define NCB (P / CPB)   // 16 col-blocks
#define NBLK (NRB * NCB)   // 512

typedef float f32x4 __attribute__((ext_vector_type(4)));
typedef short bf16x8 __attribute__((ext_vector_type(8)));

static __device__ __forceinline__ void gload_lds16(const void* g, void* l) {
    __builtin_amdgcn_global_load_lds(
        (const __attribute__((address_space(1))) void*)g,
        (__attribute__((address_space(3))) void*)l,
        16, 0, 0);
}

static __device__ __forceinline__ short f2bf(float f) {
    return __builtin_bit_cast(short, __float2bfloat16(f));
}

// Kernel A: fp32 -> bf16 convert + deinterleave. xe scaled by log2e/128
// (folds the /128 and the ln->log2 change of base into the MFMA inputs).
// Also initializes the completion counter (harness poisons ws with 0xAA).
__global__ __launch_bounds__(256) void convert_deint(
    const float* __restrict__ x,
    short* __restrict__ xe,      // [P][DIM] bf16 even rows, scaled LOG2E/128
    short* __restrict__ xo,      // [P][DIM] bf16 odd rows
    unsigned int* __restrict__ cnt) {

    const int idx = blockIdx.x * 256 + threadIdx.x;   // 262144 float4s total
    const int row = idx >> 5;
    const int c4 = idx & 31;

    f32x4 v = *reinterpret_cast<const f32x4*>(x + (size_t)idx * 4);
    const bool odd = row & 1;
    const float s = odd ? 1.0f : (LOG2E / 128.0f);
    short4 pk;
    pk.x = f2bf(v[0] * s); pk.y = f2bf(v[1] * s);
    pk.z = f2bf(v[2] * s); pk.w = f2bf(v[3] * s);
    short* dst = odd ? xo : xe;
    *reinterpret_cast<short4*>(&dst[(size_t)(row >> 1) * DIM + c4 * 4]) = pk;

    if (idx == 0) *cnt = 0;
}

// Kernel B: gram + exp + partial sums + side-channel; the LAST block to
// finish (completion counter, nobody spins) gathers partials and computes
// the loss, storing out[0] directly (single writer) and resetting cnt.
__global__ __launch_bounds__(256, 2) void gram_last(
    const short* __restrict__ xe,
    const short* __restrict__ xo,
    float* __restrict__ pr,     // [NCB][P] row partials
    float* __restrict__ pc,     // [NRB][P] col partials
    float* __restrict__ dv,     // [P]   acc@(p,p)     = log2e*(1+D_pos)
    float* __restrict__ civ,    // [P/2] acc@(p,2p+1)
    float* __restrict__ cjv,    // [P/2] acc@(2p,p)
    unsigned int* __restrict__ cnt,
    float* __restrict__ out) {

    __shared__ __align__(16) short Bs[2][TILE_COLS * DIM];   // 2 x 16 KB
    __shared__ float csf[4][CPB];                            // 4 KB
    __shared__ unsigned int sOld;

    const int tid = threadIdx.x;
    const int lane = tid & 63;
    const int wave = tid >> 6;
    const int cb = blockIdx.x;          // 16 col-blocks
    const int rb = blockIdx.y;          // 32 row-blocks
    const int p0 = rb * RPB;
    const int c0 = cb * CPB;
    const int lrow = lane & 15;
    const int g = lane >> 4;
    const int kgrp = g * 8;             // k offset in shorts

    const char* gB = (const char*)(xo + (size_t)c0 * DIM);
    auto stage = [&](int t) {
        char* lB = (char*)Bs[t & 1];
        const char* gt = gB + (size_t)t * (TILE_COLS * DIM * 2);
        #pragma unroll
        for (int i = 0; i < 4; ++i) {           // 16 KB = 16 x 1 KB chunks
            int Lbase = (wave * 4 + i) * 1024;  // wave-uniform LDS dest
            int L = Lbase + lane * 16;
            int src = L ^ (((L >> 8) & 7) << 4);  // inverse swizzle (involution)
            gload_lds16(gt + src, lB + Lbase);
        }
    };
    stage(0);

    // A fragments (pre-scaled bf16): rows p0 + wave*32 + m*16 + lrow.
    bf16x8 a[2][4];
    #pragma unroll
    for (int m = 0; m < 2; ++m) {
        const short* arow =
            xe + (size_t)(p0 + wave * 32 + m * 16 + lrow) * DIM + kgrp;
        #pragma unroll
        for (int k32 = 0; k32 < 4; ++k32)
            a[m][k32] = *reinterpret_cast<const bf16x8*>(arow + k32 * 32);
    }

    float rs[2][4];        // row partials [m][j]
    float cpp[NTILES][4];  // col partials [t][n]
    #pragma unroll
    for (int m = 0; m < 2; ++m)
        #pragma unroll
        for (int j = 0; j < 4; ++j) rs[m][j] = 0.0f;
    #pragma unroll
    for (int t = 0; t < NTILES; ++t)
        #pragma unroll
        for (int n = 0; n < 4; ++n) cpp[t][n] = 0.0f;

    #pragma unroll
    for (int t = 0; t < NTILES; ++t) {
        __syncthreads();                   // stage(t) landed; buffers safe
        if (t + 1 < NTILES) stage(t + 1);  // in flight across compute(t)

        const short* B = Bs[t & 1];
        f32x4 acc[2][4];
        #pragma unroll
        for (int m = 0; m < 2; ++m)
            #pragma unroll
            for (int n = 0; n < 4; ++n)
                acc[m][n] = f32x4{MLG2, MLG2, MLG2, MLG2};

        #pragma unroll
        for (int k32 = 0; k32 < 4; ++k32) {
            #pragma unroll
            for (int n = 0; n < 4; ++n) {
                int cc = n * 16 + lrow;
                int idx = (cc * DIM + k32 * 32 + kgrp) ^ ((cc & 7) << 3);
                bf16x8 b = *reinterpret_cast<const bf16x8*>(&B[idx]);
                #pragma unroll
                for (int m = 0; m < 2; ++m)
                    acc[m][n] = __builtin_amdgcn_mfma_f32_16x16x32_bf16(
                        a[m][k32], b, acc[m][n], 0, 0, 0);
            }
        }

        // Epilogue: exp2 (arg = log2e*(1+D)), reg partials, side-channel.
        // C/D layout: col = lane&15, row = (lane>>4)*4 + j (m89/m91).
        #pragma unroll
        for (int n = 0; n < 4; ++n) {
            const int C0 = c0 + t * 64 + n * 16;
            const int Cl = C0 + lrow;
            #pragma unroll
            for (int m = 0; m < 2; ++m) {
                const int R0 = p0 + wave * 32 + m * 16;
                const bool pdv = (R0 == C0);
                const bool pci = (C0 + 15 >= 2 * R0 + 1) && (C0 <= 2 * R0 + 31);
                const bool pcj = (R0 + 15 >= 2 * C0) && (R0 <= 2 * C0 + 30);
                #pragma unroll
                for (int j = 0; j < 4; ++j) {
                    float av = acc[m][n][j];
                    float e = exp2f(av);
                    rs[m][j] += e;
                    cpp[t][n] += e;
                    int Rj = R0 + g * 4 + j;
                    if (pdv && Cl == Rj)         dv[Rj] = av;
                    if (pci && Cl == 2 * Rj + 1) civ[Rj] = av;
                    if (pcj && Rj == 2 * Cl)     cjv[Cl] = av;
                }
            }
        }
    }

    // Row sums: reduce across the 16 col-lanes of each lane-group; plain store.
    #pragma unroll
    for (int m = 0; m < 2; ++m)
        #pragma unroll
        for (int j = 0; j < 4; ++j) {
            float v = rs[m][j];
            v += __shfl_xor(v, 1);
            v += __shfl_xor(v, 2);
            v += __shfl_xor(v, 4);
            v += __shfl_xor(v, 8);
            rs[m][j] = v;
        }
    if (lrow == 0) {
        #pragma unroll
        for (int m = 0; m < 2; ++m)
            #pragma unroll
            for (int j = 0; j < 4; ++j)
                pr[(size_t)cb * P + p0 + wave * 32 + m * 16 + g * 4 + j] =
                    rs[m][j];
    }

    // Col sums: shfl over row-groups, cross-wave combine via csf.
    #pragma unroll
    for (int t = 0; t < NTILES; ++t)
        #pragma unroll
        for (int n = 0; n < 4; ++n) {
            float v = cpp[t][n];
            v += __shfl_xor(v, 16);
            v += __shfl_xor(v, 32);
            if (lane < 16)
                csf[wave][t * TILE_COLS + n * 16 + lane] = v;
        }
    __syncthreads();
    if (tid < CPB)
        pc[(size_t)rb * P + c0 + tid] =
            csf[0][tid] + csf[1][tid] + csf[2][tid] + csf[3][tid];

    // ---- completion: release stores, count up; LAST block finalizes -------
    __syncthreads();                       // all stores of this block issued
    if (tid == 0) {
        __threadfence();                   // release: writeback to coherent point
        sOld = __hip_atomic_fetch_add(cnt, 1u, __ATOMIC_ACQ_REL,
                                      __HIP_MEMORY_SCOPE_AGENT);
    }
    __syncthreads();
    if (sOld != NBLK - 1) return;

    __threadfence();                       // acquire: invalidate stale lines

    float racc = 0.0f;
    #pragma unroll
    for (int q = 0; q < P / 256; ++q) {    // 16 p's per thread, coalesced
        const int p = q * 256 + tid;
        float s = 0.0f;
        #pragma unroll
        for (int b = 0; b < NCB; ++b) s += pr[(size_t)b * P + p];
        #pragma unroll
        for (int b = 0; b < NRB; ++b) s += pc[(size_t)b * P + p];

        float corr = 0.0f;
        if (p < P / 2) corr = exp2f(civ[p]) + exp2f(cjv[p]);

        float Dpos = dv[p] * LN2 - 1.0f;   // dv = log2e*(1+D) -> D
        float J = logf(EPS_F + (s - corr)) - Dpos;
        float r = fmaxf(J, 0.0f);
        racc += r * r;
    }

    #pragma unroll
    for (int off = 32; off > 0; off >>= 1) racc += __shfl_down(racc, off);
    if (lane == 0) csf[0][wave] = racc;
    __syncthreads();
    if (tid == 0) {
        out[0] = (csf[0][0] + csf[0][1] + csf[0][2] + csf[0][3]) *
                 (1.0f / 8192.0f);
        *cnt = 0;                          // self-clean for next graph replay
    }
}

extern "C" void kernel_launch(void* const* d_in, const int* in_sizes, int n_in,
                              void* d_out, int out_size, void* d_ws, size_t ws_size,
                              hipStream_t stream) {
    const float* x = (const float*)d_in[0];
    float* pr = (float*)d_ws;                     // NCB*P floats
    float* pc = pr + (size_t)NCB * P;             // NRB*P floats
    float* dv = pc + (size_t)NRB * P;             // P
    float* civ = dv + P;                          // P/2
    float* cjv = civ + P / 2;                     // P/2
    short* xe = (short*)(cjv + P / 2);            // P*DIM bf16
    short* xo = xe + (size_t)P * DIM;             // P*DIM bf16
    unsigned int* cnt = (unsigned int*)(xo + (size_t)P * DIM);

    convert_deint<<<1024, 256, 0, stream>>>(x, xe, xo, cnt);
    dim3 grid(NCB, NRB);   // (16, 32) = 512 blocks
    gram_last<<<grid, 256, 0, stream>>>(xe, xo, pr, pc, dv, civ, cjv, cnt,
                                        (float*)d_out);
}

// Round 12
// 35.800 us; speedup vs baseline: 2.9997x; 2.9997x over previous
//
#include <hip/hip_runtime.h>
#include <hip/hip_bf16.h>
#include <math.h>

#define P 4096          // number of (even,odd) pairs = B/2
#define DIM 128
#define EPS_F 1e-8f
#define LOG2E 1.4426950408889634f
#define LN2   0.6931471805599453f
#define MLG2  LOG2E     // MARGIN(=1)*log2e folded into acc init

#define RPB 128         // rows per block (4 waves x 32)
#define CPB 256         // cols per block (4 tiles of 64)
#define NTILES 4
#define NRB (P / RPB)   // 32 row-blocks
#define NCB (P / CPB)   // 16 col-blocks

typedef float f32x4 __attribute__((ext_vector_type(4)));
typedef short bf16x8 __attribute__((ext_vector_type(8)));

static __device__ __forceinline__ short f2bf(float f) {
    return __builtin_bit_cast(short, __float2bfloat16(f));
}

// Fragment-tiled layout: element (row C, k) lives at short index
//   ((C>>4)*4 + (k>>5))*512 + ((C&15)*4 + ((k>>3)&3))*8 + (k&7)
// so one MFMA fragment load (16 rows x one 8-k group per lane-quad) is a
// single contiguous, fully-coalesced 1 KB global_load_dwordx4 per wave.
#define TILE16(t16, k32) (((t16) * 4 + (k32)) * 512)

// Kernel A: fp32 -> bf16 convert + deinterleave into the tiled layout.
// Even rows (xe) pre-scaled by log2e/128.
__global__ __launch_bounds__(256) void convert_deint(
    const float* __restrict__ x,
    short* __restrict__ xeT,
    short* __restrict__ xoT) {

    const int idx = blockIdx.x * 256 + threadIdx.x;   // 262144 float4s
    const int row = idx >> 5;
    const int k0 = (idx & 31) * 4;

    f32x4 v = *reinterpret_cast<const f32x4*>(x + (size_t)idx * 4);
    const bool odd = row & 1;
    const float s = odd ? 1.0f : (LOG2E / 128.0f);
    short4 pk;
    pk.x = f2bf(v[0] * s); pk.y = f2bf(v[1] * s);
    pk.z = f2bf(v[2] * s); pk.w = f2bf(v[3] * s);

    const int C = row >> 1;
    const int di = TILE16(C >> 4, k0 >> 5) +
                   ((C & 15) * 4 + ((k0 >> 3) & 3)) * 8 + (k0 & 7);
    short* dst = odd ? xoT : xeT;
    *reinterpret_cast<short4*>(&dst[di]) = pk;
}

// Kernel B: LDS-free, barrier-free gram. Each wave: 32 rows x 256 cols,
// B-fragments loaded straight from L2 (tiled layout -> 1 KB coalesced loads),
// 128 MFMAs, exp2 epilogue with register partials + side-channel extraction.
__global__ __launch_bounds__(256, 2) void gram_mfma(
    const short* __restrict__ xeT,
    const short* __restrict__ xoT,
    float* __restrict__ pr,     // [NCB][P] row partials
    float* __restrict__ pc,     // [NRB][P] col partials
    float* __restrict__ dv,     // [P]   acc@(p,p)   = log2e*(1+D_pos)
    float* __restrict__ civ,    // [P/2] acc@(p,2p+1)
    float* __restrict__ cjv,    // [P/2] acc@(2p,p)
    float* __restrict__ out) {

    __shared__ float csf[4][CPB];   // 4 KB, end-reduce only

    const int tid = threadIdx.x;
    const int lane = tid & 63;
    const int wave = tid >> 6;
    const int cb = blockIdx.x;      // 16 col-blocks
    const int rb = blockIdx.y;      // 32 row-blocks
    const int p0 = rb * RPB;
    const int c0 = cb * CPB;
    const int lrow = lane & 15;
    const int g = lane >> 4;
    const int loff = (lrow * 4 + g) * 8;   // per-lane offset inside a 1 KB tile

    if (cb == 0 && rb == 0 && tid == 0) out[0] = 0.0f;  // ordered before finalize

    // A fragments: rows p0 + wave*32 + m*16 + lrow (tiled layout, 1 KB loads).
    const int at16 = (p0 >> 4) + wave * 2;
    bf16x8 a[2][4];
    #pragma unroll
    for (int m = 0; m < 2; ++m)
        #pragma unroll
        for (int k32 = 0; k32 < 4; ++k32)
            a[m][k32] = *reinterpret_cast<const bf16x8*>(
                &xeT[TILE16(at16 + m, k32) + loff]);

    float rs[2][4];        // row partials [m][j]
    float cpp[NTILES][4];  // col partials [t][n]
    #pragma unroll
    for (int m = 0; m < 2; ++m)
        #pragma unroll
        for (int j = 0; j < 4; ++j) rs[m][j] = 0.0f;
    #pragma unroll
    for (int t = 0; t < NTILES; ++t)
        #pragma unroll
        for (int n = 0; n < 4; ++n) cpp[t][n] = 0.0f;

    const int bt16 = c0 >> 4;

    #pragma unroll
    for (int t = 0; t < NTILES; ++t) {
        f32x4 acc[2][4];
        #pragma unroll
        for (int m = 0; m < 2; ++m)
            #pragma unroll
            for (int n = 0; n < 4; ++n)
                acc[m][n] = f32x4{MLG2, MLG2, MLG2, MLG2};

        #pragma unroll
        for (int k32 = 0; k32 < 4; ++k32) {
            bf16x8 b[4];
            #pragma unroll
            for (int n = 0; n < 4; ++n)
                b[n] = *reinterpret_cast<const bf16x8*>(
                    &xoT[TILE16(bt16 + t * 4 + n, k32) + loff]);
            #pragma unroll
            for (int n = 0; n < 4; ++n)
                #pragma unroll
                for (int m = 0; m < 2; ++m)
                    acc[m][n] = __builtin_amdgcn_mfma_f32_16x16x32_bf16(
                        a[m][k32], b[n], acc[m][n], 0, 0, 0);
        }

        // Epilogue: exp2 (arg = log2e*(1+D)), reg partials, side-channel.
        // C/D layout: col = lane&15, row = (lane>>4)*4 + j (m89/m91).
        #pragma unroll
        for (int n = 0; n < 4; ++n) {
            const int C0 = c0 + t * 64 + n * 16;
            const int Cl = C0 + lrow;
            #pragma unroll
            for (int m = 0; m < 2; ++m) {
                const int R0 = p0 + wave * 32 + m * 16;
                const bool pdv = (R0 == C0);
                const bool pci = (C0 + 15 >= 2 * R0 + 1) && (C0 <= 2 * R0 + 31);
                const bool pcj = (R0 + 15 >= 2 * C0) && (R0 <= 2 * C0 + 30);
                #pragma unroll
                for (int j = 0; j < 4; ++j) {
                    float av = acc[m][n][j];
                    float e = exp2f(av);
                    rs[m][j] += e;
                    cpp[t][n] += e;
                    int Rj = R0 + g * 4 + j;
                    if (pdv && Cl == Rj)         dv[Rj] = av;
                    if (pci && Cl == 2 * Rj + 1) civ[Rj] = av;
                    if (pcj && Rj == 2 * Cl)     cjv[Cl] = av;
                }
            }
        }
    }

    // Row sums: reduce across the 16 col-lanes of each lane-group; plain store.
    #pragma unroll
    for (int m = 0; m < 2; ++m)
        #pragma unroll
        for (int j = 0; j < 4; ++j) {
            float v = rs[m][j];
            v += __shfl_xor(v, 1);
            v += __shfl_xor(v, 2);
            v += __shfl_xor(v, 4);
            v += __shfl_xor(v, 8);
            rs[m][j] = v;
        }
    if (lrow == 0) {
        #pragma unroll
        for (int m = 0; m < 2; ++m)
            #pragma unroll
            for (int j = 0; j < 4; ++j)
                pr[(size_t)cb * P + p0 + wave * 32 + m * 16 + g * 4 + j] =
                    rs[m][j];
    }

    // Col sums: shfl over row-groups, cross-wave combine via csf.
    #pragma unroll
    for (int t = 0; t < NTILES; ++t)
        #pragma unroll
        for (int n = 0; n < 4; ++n) {
            float v = cpp[t][n];
            v += __shfl_xor(v, 16);
            v += __shfl_xor(v, 32);
            if (lane < 16)
                csf[wave][t * 64 + n * 16 + lane] = v;
        }
    __syncthreads();
    if (tid < CPB)
        pc[(size_t)rb * P + c0 + tid] =
            csf[0][tid] + csf[1][tid] + csf[2][tid] + csf[3][tid];
}

// Finalize: tiny — 0.85 MB of partials + side-channel values, no x reads.
__global__ __launch_bounds__(256) void finalize(
    const float* __restrict__ pr,
    const float* __restrict__ pc,
    const float* __restrict__ dv,
    const float* __restrict__ civ,
    const float* __restrict__ cjv,
    float* __restrict__ out) {

    __shared__ float wsum[4];
    const int tid = threadIdx.x;
    const int lane = tid & 63;
    const int wave = tid >> 6;
    const int p = blockIdx.x * 256 + tid;   // grid = 16 -> p in [0,P)

    float s = 0.0f;
    #pragma unroll
    for (int b = 0; b < NCB; ++b) s += pr[(size_t)b * P + p];
    #pragma unroll
    for (int b = 0; b < NRB; ++b) s += pc[(size_t)b * P + p];

    float corr = 0.0f;
    if (p < P / 2) corr = exp2f(civ[p]) + exp2f(cjv[p]);

    float Dpos = dv[p] * LN2 - 1.0f;      // dv = log2e*(1+D) -> D
    float J = logf(EPS_F + (s - corr)) - Dpos;
    float r = fmaxf(J, 0.0f);
    r = r * r;

    #pragma unroll
    for (int off = 32; off > 0; off >>= 1) r += __shfl_down(r, off);
    if (lane == 0) wsum[wave] = r;
    __syncthreads();
    if (tid == 0)
        atomicAdd(out, (wsum[0] + wsum[1] + wsum[2] + wsum[3]) *
                           (1.0f / 8192.0f));
}

extern "C" void kernel_launch(void* const* d_in, const int* in_sizes, int n_in,
                              void* d_out, int out_size, void* d_ws, size_t ws_size,
                              hipStream_t stream) {
    const float* x = (const float*)d_in[0];
    float* pr = (float*)d_ws;                     // NCB*P floats
    float* pc = pr + (size_t)NCB * P;             // NRB*P floats
    float* dv = pc + (size_t)NRB * P;             // P
    float* civ = dv + P;                          // P/2
    float* cjv = civ + P / 2;                     // P/2
    short* xeT = (short*)(cjv + P / 2);           // P*DIM bf16 (tiled)
    short* xoT = xeT + (size_t)P * DIM;           // P*DIM bf16 (tiled)

    convert_deint<<<1024, 256, 0, stream>>>(x, xeT, xoT);
    dim3 grid(NCB, NRB);   // (16, 32) = 512 blocks
    gram_mfma<<<grid, 256, 0, stream>>>(xeT, xoT, pr, pc, dv, civ, cjv,
                                        (float*)d_out);
    finalize<<<P / 256, 256, 0, stream>>>(pr, pc, dv, civ, cjv, (float*)d_out);
}

// Round 13
// 31.265 us; speedup vs baseline: 3.4348x; 1.1450x over previous
//
#include <hip/hip_runtime.h>
#include <hip/hip_bf16.h>
#include <math.h>

#define P 4096          // number of (even,odd) pairs = B/2
#define DIM 128
#define EPS_F 1e-8f
#define LOG2E 1.4426950408889634f
#define LN2   0.6931471805599453f
#define MLG2  LOG2E     // MARGIN(=1)*log2e folded into acc init

#define RPB 128         // rows per block (4 waves x 32)
#define CPB 128         // cols per block (2 tiles of 64)
#define NTILES 2
#define NRB (P / RPB)   // 32 row-blocks
#define NCB (P / CPB)   // 32 col-blocks

typedef float f32x4 __attribute__((ext_vector_type(4)));
typedef short bf16x8 __attribute__((ext_vector_type(8)));

static __device__ __forceinline__ short f2bf(float f) {
    return __builtin_bit_cast(short, __float2bfloat16(f));
}

// Fragment-tiled layout: element (row C, k) lives at short index
//   ((C>>4)*4 + (k>>5))*512 + ((C&15)*4 + ((k>>3)&3))*8 + (k&7)
// so one MFMA fragment load (16 rows x one 8-k group per lane) is a single
// contiguous, fully-coalesced 1 KB global load per wave.
#define TILE16(t16, k32) (((t16) * 4 + (k32)) * 512)

// Kernel A: fp32 -> bf16 convert + deinterleave into the tiled layout.
// Even rows (xe) pre-scaled by log2e/128.
__global__ __launch_bounds__(256) void convert_deint(
    const float* __restrict__ x,
    short* __restrict__ xeT,
    short* __restrict__ xoT) {

    const int idx = blockIdx.x * 256 + threadIdx.x;   // 262144 float4s
    const int row = idx >> 5;
    const int k0 = (idx & 31) * 4;

    f32x4 v = *reinterpret_cast<const f32x4*>(x + (size_t)idx * 4);
    const bool odd = row & 1;
    const float s = odd ? 1.0f : (LOG2E / 128.0f);
    short4 pk;
    pk.x = f2bf(v[0] * s); pk.y = f2bf(v[1] * s);
    pk.z = f2bf(v[2] * s); pk.w = f2bf(v[3] * s);

    const int C = row >> 1;
    const int di = TILE16(C >> 4, k0 >> 5) +
                   ((C & 15) * 4 + ((k0 >> 3) & 3)) * 8 + (k0 & 7);
    short* dst = odd ? xoT : xeT;
    *reinterpret_cast<short4*>(&dst[di]) = pk;
}

// Kernel B: LDS-free, barrier-free gram with register-double-buffered
// B-fragment prefetch (loads issued one k-step ahead of the MFMAs that
// consume them). 1024 blocks -> 4 blocks/CU, 16 waves/CU.
__global__ __launch_bounds__(256, 4) void gram_mfma(
    const short* __restrict__ xeT,
    const short* __restrict__ xoT,
    float* __restrict__ pr,     // [NCB][P] row partials
    float* __restrict__ pc,     // [NRB][P] col partials
    float* __restrict__ dv,     // [P]   acc@(p,p)   = log2e*(1+D_pos)
    float* __restrict__ civ,    // [P/2] acc@(p,2p+1)
    float* __restrict__ cjv,    // [P/2] acc@(2p,p)
    float* __restrict__ out) {

    __shared__ float csf[4][CPB];   // 2 KB, end-reduce only

    const int tid = threadIdx.x;
    const int lane = tid & 63;
    const int wave = tid >> 6;
    const int cb = blockIdx.x;      // 32 col-blocks
    const int rb = blockIdx.y;      // 32 row-blocks
    const int p0 = rb * RPB;
    const int c0 = cb * CPB;
    const int lrow = lane & 15;
    const int g = lane >> 4;
    const int loff = (lrow * 4 + g) * 8;   // per-lane offset inside a 1 KB tile
    const int bt16 = c0 >> 4;

    if (cb == 0 && rb == 0 && tid == 0) out[0] = 0.0f;  // ordered before finalize

    // B-fragment register double buffer (all indices compile-time static).
    bf16x8 bb[2][4];
    #pragma unroll
    for (int n = 0; n < 4; ++n)
        bb[0][n] = *reinterpret_cast<const bf16x8*>(
            &xoT[TILE16(bt16 + n, 0) + loff]);

    // A fragments: rows p0 + wave*32 + m*16 + lrow (1 KB coalesced loads).
    const int at16 = (p0 >> 4) + wave * 2;
    bf16x8 a[2][4];
    #pragma unroll
    for (int m = 0; m < 2; ++m)
        #pragma unroll
        for (int k32 = 0; k32 < 4; ++k32)
            a[m][k32] = *reinterpret_cast<const bf16x8*>(
                &xeT[TILE16(at16 + m, k32) + loff]);

    float rs[2][4];        // row partials [m][j]
    float cpp[NTILES][4];  // col partials [t][n]
    #pragma unroll
    for (int m = 0; m < 2; ++m)
        #pragma unroll
        for (int j = 0; j < 4; ++j) rs[m][j] = 0.0f;
    #pragma unroll
    for (int t = 0; t < NTILES; ++t)
        #pragma unroll
        for (int n = 0; n < 4; ++n) cpp[t][n] = 0.0f;

    #pragma unroll
    for (int t = 0; t < NTILES; ++t) {
        f32x4 acc[2][4];
        #pragma unroll
        for (int m = 0; m < 2; ++m)
            #pragma unroll
            for (int n = 0; n < 4; ++n)
                acc[m][n] = f32x4{MLG2, MLG2, MLG2, MLG2};

        #pragma unroll
        for (int k32 = 0; k32 < 4; ++k32) {
            const int step = t * 4 + k32;            // 0..7, compile-time
            if (step + 1 < NTILES * 4) {             // prefetch next k-step
                const int s1 = step + 1;
                #pragma unroll
                for (int n = 0; n < 4; ++n)
                    bb[s1 & 1][n] = *reinterpret_cast<const bf16x8*>(
                        &xoT[TILE16(bt16 + (s1 >> 2) * 4 + n, s1 & 3) + loff]);
            }
            #pragma unroll
            for (int n = 0; n < 4; ++n)
                #pragma unroll
                for (int m = 0; m < 2; ++m)
                    acc[m][n] = __builtin_amdgcn_mfma_f32_16x16x32_bf16(
                        a[m][k32], bb[step & 1][n], acc[m][n], 0, 0, 0);
        }

        // Epilogue: exp2 (arg = log2e*(1+D)), reg partials, side-channel.
        // C/D layout: col = lane&15, row = (lane>>4)*4 + j (m89/m91).
        #pragma unroll
        for (int n = 0; n < 4; ++n) {
            const int C0 = c0 + t * 64 + n * 16;
            const int Cl = C0 + lrow;
            #pragma unroll
            for (int m = 0; m < 2; ++m) {
                const int R0 = p0 + wave * 32 + m * 16;
                const bool pdv = (R0 == C0);
                const bool pci = (C0 + 15 >= 2 * R0 + 1) && (C0 <= 2 * R0 + 31);
                const bool pcj = (R0 + 15 >= 2 * C0) && (R0 <= 2 * C0 + 30);
                #pragma unroll
                for (int j = 0; j < 4; ++j) {
                    float av = acc[m][n][j];
                    float e = exp2f(av);
                    rs[m][j] += e;
                    cpp[t][n] += e;
                    int Rj = R0 + g * 4 + j;
                    if (pdv && Cl == Rj)         dv[Rj] = av;
                    if (pci && Cl == 2 * Rj + 1) civ[Rj] = av;
                    if (pcj && Rj == 2 * Cl)     cjv[Cl] = av;
                }
            }
        }
    }

    // Row sums: reduce across the 16 col-lanes of each lane-group; plain store.
    #pragma unroll
    for (int m = 0; m < 2; ++m)
        #pragma unroll
        for (int j = 0; j < 4; ++j) {
            float v = rs[m][j];
            v += __shfl_xor(v, 1);
            v += __shfl_xor(v, 2);
            v += __shfl_xor(v, 4);
            v += __shfl_xor(v, 8);
            rs[m][j] = v;
        }
    if (lrow == 0) {
        #pragma unroll
        for (int m = 0; m < 2; ++m)
            #pragma unroll
            for (int j = 0; j < 4; ++j)
                pr[(size_t)cb * P + p0 + wave * 32 + m * 16 + g * 4 + j] =
                    rs[m][j];
    }

    // Col sums: shfl over row-groups, cross-wave combine via csf.
    #pragma unroll
    for (int t = 0; t < NTILES; ++t)
        #pragma unroll
        for (int n = 0; n < 4; ++n) {
            float v = cpp[t][n];
            v += __shfl_xor(v, 16);
            v += __shfl_xor(v, 32);
            if (lane < 16)
                csf[wave][t * 64 + n * 16 + lane] = v;
        }
    __syncthreads();
    if (tid < CPB)
        pc[(size_t)rb * P + c0 + tid] =
            csf[0][tid] + csf[1][tid] + csf[2][tid] + csf[3][tid];
}

// Finalize: tiny — ~1 MB of partials + side-channel values, no x reads.
__global__ __launch_bounds__(256) void finalize(
    const float* __restrict__ pr,
    const float* __restrict__ pc,
    const float* __restrict__ dv,
    const float* __restrict__ civ,
    const float* __restrict__ cjv,
    float* __restrict__ out) {

    __shared__ float wsum[4];
    const int tid = threadIdx.x;
    const int lane = tid & 63;
    const int wave = tid >> 6;
    const int p = blockIdx.x * 256 + tid;   // grid = 16 -> p in [0,P)

    float s = 0.0f;
    #pragma unroll
    for (int b = 0; b < NCB; ++b) s += pr[(size_t)b * P + p];
    #pragma unroll
    for (int b = 0; b < NRB; ++b) s += pc[(size_t)b * P + p];

    float corr = 0.0f;
    if (p < P / 2) corr = exp2f(civ[p]) + exp2f(cjv[p]);

    float Dpos = dv[p] * LN2 - 1.0f;      // dv = log2e*(1+D) -> D
    float J = logf(EPS_F + (s - corr)) - Dpos;
    float r = fmaxf(J, 0.0f);
    r = r * r;

    #pragma unroll
    for (int off = 32; off > 0; off >>= 1) r += __shfl_down(r, off);
    if (lane == 0) wsum[wave] = r;
    __syncthreads();
    if (tid == 0)
        atomicAdd(out, (wsum[0] + wsum[1] + wsum[2] + wsum[3]) *
                           (1.0f / 8192.0f));
}

extern "C" void kernel_launch(void* const* d_in, const int* in_sizes, int n_in,
                              void* d_out, int out_size, void* d_ws, size_t ws_size,
                              hipStream_t stream) {
    const float* x = (const float*)d_in[0];
    float* pr = (float*)d_ws;                     // NCB*P floats
    float* pc = pr + (size_t)NCB * P;             // NRB*P floats
    float* dv = pc + (size_t)NRB * P;             // P
    float* civ = dv + P;                          // P/2
    float* cjv = civ + P / 2;                     // P/2
    short* xeT = (short*)(cjv + P / 2);           // P*DIM bf16 (tiled)
    short* xoT = xeT + (size_t)P * DIM;           // P*DIM bf16 (tiled)

    convert_deint<<<1024, 256, 0, stream>>>(x, xeT, xoT);
    dim3 grid(NCB, NRB);   // (32, 32) = 1024 blocks
    gram_mfma<<<grid, 256, 0, stream>>>(xeT, xoT, pr, pc, dv, civ, cjv,
                                        (float*)d_out);
    finalize<<<P / 256, 256, 0, stream>>>(pr, pc, dv, civ, cjv, (float*)d_out);
}

// Round 14
// 30.410 us; speedup vs baseline: 3.5313x; 1.0281x over previous
//
#include <hip/hip_runtime.h>
#include <hip/hip_bf16.h>
#include <math.h>

#define P 4096          // number of (even,odd) pairs = B/2
#define DIM 128
#define MARGIN_F 1.0f
#define EPS_F 1e-8f

#define RPB 128         // rows per block (4 waves x 32)
#define CPB 128         // cols per block (2 tiles of 64)
#define TILE_COLS 64
#define NTILES 2
#define NRB (P / RPB)   // 32
#define NCB (P / CPB)   // 32

typedef float f32x4 __attribute__((ext_vector_type(4)));
typedef short bf16x8 __attribute__((ext_vector_type(8)));

static __device__ __forceinline__ void gload_lds16(const void* g, void* l) {
    __builtin_amdgcn_global_load_lds(
        (const __attribute__((address_space(1))) void*)g,
        (__attribute__((address_space(3))) void*)l,
        16, 0, 0);
}

// Kernel A: fp32 -> bf16 convert + deinterleave. xe pre-scaled by 1/128
// (exact exponent shift). Also zeroes rowsum/colsum/out.
__global__ __launch_bounds__(256) void convert_deint(
    const float* __restrict__ x,
    short* __restrict__ xe,      // [P][DIM] bf16 of even rows, scaled 1/128
    short* __restrict__ xo,      // [P][DIM] bf16 of odd rows
    float* __restrict__ rowcol,  // 2*P floats to zero
    float* __restrict__ out) {

    const int idx = blockIdx.x * 256 + threadIdx.x;   // 262144 float4s total
    const int row = idx >> 5;
    const int c4 = idx & 31;

    f32x4 v = *reinterpret_cast<const f32x4*>(x + (size_t)idx * 4);
    const bool odd = row & 1;
    const float s = odd ? 1.0f : 0.0078125f;   // even rows (xe) scaled 1/128
    short4 pk;
    pk.x = __builtin_bit_cast(short, __float2bfloat16(v[0] * s));
    pk.y = __builtin_bit_cast(short, __float2bfloat16(v[1] * s));
    pk.z = __builtin_bit_cast(short, __float2bfloat16(v[2] * s));
    pk.w = __builtin_bit_cast(short, __float2bfloat16(v[3] * s));
    short* dst = odd ? xo : xe;
    *reinterpret_cast<short4*>(&dst[(size_t)(row >> 1) * DIM + c4 * 4]) = pk;

    if (idx < 2 * P) rowcol[idx] = 0.0f;
    if (idx == 0) out[0] = 0.0f;
}

// Kernel B: R6 structure, occupancy doubled (CPB 256->128, NTILES 4->2,
// grid 512->1024 blocks = 4 blocks/CU, 16 waves/CU).
__global__ __launch_bounds__(256, 4) void gram_mfma(
    const short* __restrict__ xe,
    const short* __restrict__ xo,
    float* __restrict__ rowsum,
    float* __restrict__ colsum) {

    __shared__ __align__(16) short Bs[2][TILE_COLS * DIM];   // 2 x 16 KB
    __shared__ float csf[4][CPB];                            // 2 KB

    const int tid = threadIdx.x;
    const int lane = tid & 63;
    const int wave = tid >> 6;
    const int p0 = blockIdx.y * RPB;
    const int c0 = blockIdx.x * CPB;
    const int lrow = lane & 15;
    const int kgrp = (lane >> 4) * 8;   // k offset in shorts

    const char* gB = (const char*)(xo + (size_t)c0 * DIM);
    auto stage = [&](int t) {
        char* lB = (char*)Bs[t & 1];
        const char* gt = gB + (size_t)t * (TILE_COLS * DIM * 2);
        #pragma unroll
        for (int i = 0; i < 4; ++i) {           // 16 KB = 16 x 1 KB chunks
            int Lbase = (wave * 4 + i) * 1024;  // wave-uniform LDS dest
            int L = Lbase + lane * 16;
            int src = L ^ (((L >> 8) & 7) << 4);  // inverse swizzle (involution)
            gload_lds16(gt + src, lB + Lbase);
        }
    };
    stage(0);

    // A fragments in registers: rows p0 + wave*32 + m*16 + lrow, 4 k-steps.
    bf16x8 a[2][4];
    #pragma unroll
    for (int m = 0; m < 2; ++m) {
        const short* arow =
            xe + (size_t)(p0 + wave * 32 + m * 16 + lrow) * DIM + kgrp;
        #pragma unroll
        for (int k32 = 0; k32 < 4; ++k32)
            a[m][k32] = *reinterpret_cast<const bf16x8*>(arow + k32 * 32);
    }

    float rs[2][4];        // row partials [m][j]
    float cpp[NTILES][4];  // col partials [t][n]
    #pragma unroll
    for (int m = 0; m < 2; ++m)
        #pragma unroll
        for (int j = 0; j < 4; ++j) rs[m][j] = 0.0f;
    #pragma unroll
    for (int t = 0; t < NTILES; ++t)
        #pragma unroll
        for (int n = 0; n < 4; ++n) cpp[t][n] = 0.0f;

    #pragma unroll
    for (int t = 0; t < NTILES; ++t) {
        // Barrier: (a) vmcnt drains -> stage(t) landed; (b) all waves done
        // with compute(t-1), so Bs[(t+1)&1] is safe to overwrite.
        __syncthreads();
        if (t + 1 < NTILES) stage(t + 1);   // in flight across compute(t)

        const short* B = Bs[t & 1];
        f32x4 acc[2][4];
        #pragma unroll
        for (int m = 0; m < 2; ++m)
            #pragma unroll
            for (int n = 0; n < 4; ++n) acc[m][n] = f32x4{0.f, 0.f, 0.f, 0.f};

        #pragma unroll
        for (int k32 = 0; k32 < 4; ++k32) {
            #pragma unroll
            for (int n = 0; n < 4; ++n) {
                int cc = n * 16 + lrow;
                int idx = (cc * DIM + k32 * 32 + kgrp) ^ ((cc & 7) << 3);
                bf16x8 b = *reinterpret_cast<const bf16x8*>(&B[idx]);
                #pragma unroll
                for (int m = 0; m < 2; ++m)
                    acc[m][n] = __builtin_amdgcn_mfma_f32_16x16x32_bf16(
                        a[m][k32], b, acc[m][n], 0, 0, 0);
            }
        }

        // Epilogue: exp, all partials in registers.
        // C/D layout: col = lane&15, row = (lane>>4)*4 + j (m89/m91).
        #pragma unroll
        for (int n = 0; n < 4; ++n)
            #pragma unroll
            for (int m = 0; m < 2; ++m)
                #pragma unroll
                for (int j = 0; j < 4; ++j) {
                    float e = __expf(MARGIN_F + acc[m][n][j]);
                    rs[m][j] += e;
                    cpp[t][n] += e;
                }
    }

    // Row sums: reduce across the 16 col-lanes of each lane-group.
    #pragma unroll
    for (int m = 0; m < 2; ++m)
        #pragma unroll
        for (int j = 0; j < 4; ++j) {
            float v = rs[m][j];
            v += __shfl_xor(v, 1);
            v += __shfl_xor(v, 2);
            v += __shfl_xor(v, 4);
            v += __shfl_xor(v, 8);
            rs[m][j] = v;
        }
    if (lrow == 0) {
        int g = lane >> 4;
        #pragma unroll
        for (int m = 0; m < 2; ++m)
            #pragma unroll
            for (int j = 0; j < 4; ++j)
                atomicAdd(&rowsum[p0 + wave * 32 + m * 16 + g * 4 + j],
                          rs[m][j]);
    }

    // Col sums: shfl over row-groups, cross-wave combine via csf,
    // one atomic per col.
    #pragma unroll
    for (int t = 0; t < NTILES; ++t)
        #pragma unroll
        for (int n = 0; n < 4; ++n) {
            float v = cpp[t][n];
            v += __shfl_xor(v, 16);
            v += __shfl_xor(v, 32);
            if (lane < 16)
                csf[wave][t * TILE_COLS + n * 16 + lane] = v;
        }
    __syncthreads();
    if (tid < CPB)
        atomicAdd(&colsum[c0 + tid],
                  csf[0][tid] + csf[1][tid] + csf[2][tid] + csf[3][tid]);
}

// Kernel C: per-p corrections + J + loss (fp32 exact). 16 pairs per block.
__global__ __launch_bounds__(256) void finalize(
    const float* __restrict__ x,
    const float* __restrict__ rowsum,
    const float* __restrict__ colsum,
    float* __restrict__ out) {

    __shared__ float wsum[4];
    const int tid = threadIdx.x;
    const int wave = tid >> 6;
    const int lane = tid & 63;

    float racc = 0.0f;
    #pragma unroll
    for (int q = 0; q < 4; ++q) {
        const int p = blockIdx.x * 16 + wave * 4 + q;

        const float2* xep = reinterpret_cast<const float2*>(x + (size_t)(2 * p) * DIM);
        const float2* xop = reinterpret_cast<const float2*>(x + (size_t)(2 * p + 1) * DIM);
        float2 ve = xep[lane];
        float2 vo = xop[lane];
        float dpos = ve.x * vo.x + ve.y * vo.y;

        float ci = 0.0f, cj = 0.0f;
        if (p < P / 2) {
            const float2* xi = reinterpret_cast<const float2*>(x + (size_t)(4 * p + 3) * DIM);
            const float2* xj = reinterpret_cast<const float2*>(x + (size_t)(4 * p) * DIM);
            float2 vi = xi[lane];
            float2 vj = xj[lane];
            ci = ve.x * vi.x + ve.y * vi.y;   // dot(x[2p],   x[4p+3])
            cj = vo.x * vj.x + vo.y * vj.y;   // dot(x[2p+1], x[4p])
        }

        #pragma unroll
        for (int off = 32; off > 0; off >>= 1) {
            dpos += __shfl_down(dpos, off);
            ci   += __shfl_down(ci, off);
            cj   += __shfl_down(cj, off);
        }

        if (lane == 0) {
            float corr = 0.0f;
            if (p < P / 2)
                corr = __expf(MARGIN_F + ci * (1.0f / 128.0f))
                     + __expf(MARGIN_F + cj * (1.0f / 128.0f));
            float neg = rowsum[p] + colsum[p] - corr;
            float J = logf(EPS_F + neg) - dpos * (1.0f / 128.0f);
            float r = fmaxf(J, 0.0f);
            racc += r * r;
        }
    }

    if (lane == 0) wsum[wave] = racc;
    __syncthreads();
    if (tid == 0) {
        float s = (wsum[0] + wsum[1] + wsum[2] + wsum[3]) * (1.0f / 8192.0f);
        atomicAdd(out, s);
    }
}

extern "C" void kernel_launch(void* const* d_in, const int* in_sizes, int n_in,
                              void* d_out, int out_size, void* d_ws, size_t ws_size,
                              hipStream_t stream) {
    const float* x = (const float*)d_in[0];
    float* rowsum = (float*)d_ws;
    float* colsum = rowsum + P;
    short* xe = (short*)(colsum + P);
    short* xo = xe + (size_t)P * DIM;

    convert_deint<<<1024, 256, 0, stream>>>(x, xe, xo, rowsum, (float*)d_out);
    dim3 grid(NCB, NRB);  // (32, 32) = 1024 blocks, 4 blocks/CU
    gram_mfma<<<grid, 256, 0, stream>>>(xe, xo, rowsum, colsum);
    finalize<<<P / 16, 256, 0, stream>>>(x, rowsum, colsum, (float*)d_out);
}